// Round 2
// 221.141 us; speedup vs baseline: 1.0531x; 1.0531x over previous
//
#include <hip/hip_runtime.h>
#include <hip/hip_bf16.h>

#define NBATCH 256
#define NT 512
#define ND 256
#define NROWS (NBATCH * NT)
#define NCHUNK (NROWS / 64)     // 2048 blocks, 8 chunks per batch

typedef __attribute__((ext_vector_type(8))) short short8;
typedef __attribute__((ext_vector_type(4))) float floatx4;

__device__ __forceinline__ unsigned short f2bf(float x) {
    // round-to-nearest-even fp32 -> bf16
    unsigned int u = __float_as_uint(x);
    u += 0x7FFFu + ((u >> 16) & 1u);
    return (unsigned short)(u >> 16);
}

// prep: W fp32 [D,D] (e,d) -> bf16 chunks in MFMA-FRAG ORDER.
// chunk g (16B = 8 bf16) = nb*512 + s*64 + q*16 + m
//   <-> W[e = nb*16 + m][k = q*8 + s*32 .. +8]
__global__ void __launch_bounds__(256) prep_kernel(
    const float* __restrict__ W, unsigned short* __restrict__ wf)
{
    int g  = blockIdx.x * 256 + threadIdx.x;   // 8192 chunks
    int m  = g & 15, q = (g >> 4) & 3, s = (g >> 6) & 7, nb = g >> 9;
    const float* src = W + (nb * 16 + m) * ND + q * 8 + s * 32;
    float4 f0 = *(const float4*)src;
    float4 f1 = *(const float4*)(src + 4);
    short8 v;
    v[0] = (short)f2bf(f0.x); v[1] = (short)f2bf(f0.y);
    v[2] = (short)f2bf(f0.z); v[3] = (short)f2bf(f0.w);
    v[4] = (short)f2bf(f1.x); v[5] = (short)f2bf(f1.y);
    v[6] = (short)f2bf(f1.z); v[7] = (short)f2bf(f1.w);
    *(short8*)(wf + (long)g * 8) = v;
}

// FUSED: scores (MFMA+tanh) -> chunk-local softmax -> chunk weighted sum.
// Block = 64 consecutive bt-rows (one chunk, always within a single batch
// since 512 % 64 == 0). 4 waves, one 16-row MFMA tile per wave.
// Phase 2 re-reads the block's own 64KB of ip (L2/L3-hot) instead of a
// second full HBM pass: per-iteration HBM halves vs the 2-kernel version.
// Chunk partials (m_c, l_c, acc[256]) go to workspace; tiny combine merges.
__global__ void __launch_bounds__(256, 4) fused_kernel(
    const float* __restrict__ ip,             // [B*T, D] fp32
    const unsigned short* __restrict__ wf,    // frag-ordered W bf16
    const float* __restrict__ bias,           // [D] fp32
    const float* __restrict__ ctx,            // [D] fp32
    float* __restrict__ gpart,                // [NCHUNK, 256] fp32 partials
    float2* __restrict__ ml)                  // [NCHUNK] (max, sumexp)
{
    __shared__ __align__(16) char wsm[32768];   // W quarter staging; reused as part buf
    __shared__ float score_s[64];
    __shared__ float w_s[64];
    short8* lds16 = (short8*)wsm;

    const int tid  = threadIdx.x;
    const int lane = tid & 63;
    const int wv   = tid >> 6;        // wave 0..3
    const int m    = lane & 15;       // A row / W e-col within tile
    const int q    = lane >> 4;       // k-quad
    const long row0 = (long)blockIdx.x * 64 + wv * 16;

    // ---- A fragments: ONE tile (16 rows), loads batched 8-deep ----
    short8 a[8];
    {
        const float* ar = ip + (row0 + m) * ND + q * 8;
        float4 raw[8];
#pragma unroll
        for (int g = 0; g < 2; ++g) {
#pragma unroll
            for (int i = 0; i < 4; ++i) {
                raw[2 * i]     = *(const float4*)(ar + (4 * g + i) * 32);
                raw[2 * i + 1] = *(const float4*)(ar + (4 * g + i) * 32 + 4);
            }
#pragma unroll
            for (int i = 0; i < 4; ++i) {
                short8 v;
                v[0] = (short)f2bf(raw[2 * i].x); v[1] = (short)f2bf(raw[2 * i].y);
                v[2] = (short)f2bf(raw[2 * i].z); v[3] = (short)f2bf(raw[2 * i].w);
                v[4] = (short)f2bf(raw[2 * i + 1].x); v[5] = (short)f2bf(raw[2 * i + 1].y);
                v[6] = (short)f2bf(raw[2 * i + 1].z); v[7] = (short)f2bf(raw[2 * i + 1].w);
                a[4 * g + i] = v;
            }
        }
    }

    float sc[4] = {0.f, 0.f, 0.f, 0.f};
    const short8* wchunks = (const short8*)wf;

#pragma unroll 1
    for (int stage = 0; stage < 4; ++stage) {
        if (stage) __syncthreads();           // prior quarter's reads done
#pragma unroll
        for (int u = 0; u < 8; ++u) {
            int c = u * 256 + tid;
            lds16[c] = wchunks[stage * 2048 + c];   // chunk-linear, coalesced
        }
        __syncthreads();

#pragma unroll 1
        for (int nbl = 0; nbl < 4; ++nbl) {
            const int e = (stage * 4 + nbl) * 16 + m;
            const short8* wp = lds16 + nbl * 512 + lane;   // lane-linear b128
            short8 w[8];
#pragma unroll
            for (int s = 0; s < 8; ++s) w[s] = wp[s * 64];
            floatx4 acc = {0.f, 0.f, 0.f, 0.f};
#pragma unroll
            for (int s = 0; s < 8; ++s)
                acc = __builtin_amdgcn_mfma_f32_16x16x32_bf16(a[s], w[s], acc, 0, 0, 0);
            const float be  = bias[e];        // 1KB tables, L1-hot
            const float ce  = ctx[e];
            const float ce2 = ce + ce;
#pragma unroll
            for (int r = 0; r < 4; ++r) {     // acc[r] = D[row=q*4+r][col=m]
                float x = acc[r] + be;
                // tanh(x)*ce = ce - ce2 * rcp(exp(2x)+1)
                float t = __builtin_amdgcn_rcpf(__expf(x + x) + 1.f);
                sc[r] = __builtin_fmaf(-ce2, t, sc[r] + ce);
            }
        }
    }

    // sum over 16 e-cols spread across lanes sharing a quad (xor lane bits 0..3)
#pragma unroll
    for (int off = 8; off >= 1; off >>= 1) {
#pragma unroll
        for (int r = 0; r < 4; ++r)
            sc[r] += __shfl_xor(sc[r], off, 64);
    }
    if (m == 0) {
#pragma unroll
        for (int r = 0; r < 4; ++r)
            score_s[wv * 16 + q * 4 + r] = sc[r];   // chunk-local row
    }
    __syncthreads();    // also: all lds16 reads done -> wsm reusable below

    // ---- chunk-local softmax over 64 rows (each wave redundantly) ----
    float s = score_s[lane];
    float mx = s;
#pragma unroll
    for (int off = 32; off >= 1; off >>= 1) mx = fmaxf(mx, __shfl_xor(mx, off, 64));
    float w = __expf(s - mx);
    float lsum = w;
#pragma unroll
    for (int off = 32; off >= 1; off >>= 1) lsum += __shfl_xor(lsum, off, 64);
    if (wv == 0) w_s[lane] = w;
    if (tid == 0) ml[blockIdx.x] = make_float2(mx, lsum);
    __syncthreads();

    // ---- phase 2: weighted sum of this chunk's 64 rows (L2-hot re-read) ----
    // thread -> (float4 col c = lane, row-group g = wave). Loads: 64 lanes =
    // 1KB contiguous per instruction.
    const float4* base = (const float4*)ip + ((long)blockIdx.x * 64 + wv * 16) * 64 + lane;
    float4 acc4 = {0.f, 0.f, 0.f, 0.f};
#pragma unroll
    for (int r = 0; r < 16; ++r) {
        float wt = w_s[wv * 16 + r];          // wave-uniform LDS broadcast
        float4 v = base[(long)r * 64];
        acc4.x += wt * v.x; acc4.y += wt * v.y;
        acc4.z += wt * v.z; acc4.w += wt * v.w;
    }
    float4* part4 = (float4*)wsm;             // reuse W staging LDS (16 KB)
    part4[wv * 64 + lane] = acc4;
    __syncthreads();
    if (tid < 64) {
        float4 r0 = part4[tid],       r1 = part4[64 + tid];
        float4 r2 = part4[128 + tid], r3 = part4[192 + tid];
        float4 o;
        o.x = r0.x + r1.x + r2.x + r3.x;
        o.y = r0.y + r1.y + r2.y + r3.y;
        o.z = r0.z + r1.z + r2.z + r3.z;
        o.w = r0.w + r1.w + r2.w + r3.w;
        ((float4*)gpart)[(long)blockIdx.x * 64 + tid] = o;
    }
}

// combine: merge the 8 chunk partials of each batch with softmax rescale.
// out[b,d] = sum_c e^{m_c-M} acc_c[d] / sum_c e^{m_c-M} l_c
__global__ void __launch_bounds__(256) combine_kernel(
    const float4* __restrict__ gpart4,   // [NCHUNK, 64] float4
    const float2* __restrict__ ml,       // [NCHUNK]
    float4* __restrict__ out4)           // [B, 64] float4
{
    const int b = blockIdx.x * 4 + (threadIdx.x >> 6);   // wave -> batch
    const int c = threadIdx.x & 63;
    const float2* mlb = ml + b * 8;
    float mk[8], lk[8];
#pragma unroll
    for (int k = 0; k < 8; ++k) { float2 p = mlb[k]; mk[k] = p.x; lk[k] = p.y; }
    float M = mk[0];
#pragma unroll
    for (int k = 1; k < 8; ++k) M = fmaxf(M, mk[k]);
    float L = 0.f, f[8];
#pragma unroll
    for (int k = 0; k < 8; ++k) { f[k] = __expf(mk[k] - M); L += f[k] * lk[k]; }
    float4 acc = {0.f, 0.f, 0.f, 0.f};
#pragma unroll
    for (int k = 0; k < 8; ++k) {
        float4 v = gpart4[(long)(b * 8 + k) * 64 + c];
        acc.x += f[k] * v.x; acc.y += f[k] * v.y;
        acc.z += f[k] * v.z; acc.w += f[k] * v.w;
    }
    float inv = 1.f / L;
    acc.x *= inv; acc.y *= inv; acc.z *= inv; acc.w *= inv;
    out4[(long)b * 64 + c] = acc;
}

extern "C" void kernel_launch(void* const* d_in, const int* in_sizes, int n_in,
                              void* d_out, int out_size, void* d_ws, size_t ws_size,
                              hipStream_t stream) {
    const float* ip   = (const float*)d_in[0];
    const float* W    = (const float*)d_in[1];
    const float* bias = (const float*)d_in[2];
    const float* ctx  = (const float*)d_in[3];

    unsigned short* wf = (unsigned short*)d_ws;                              // 128 KB
    float* gpart = (float*)((char*)d_ws + ND * ND * sizeof(unsigned short)); // 2 MB
    float2* ml   = (float2*)((char*)gpart + (long)NCHUNK * ND * sizeof(float)); // 16 KB

    prep_kernel<<<32, 256, 0, stream>>>(W, wf);
    fused_kernel<<<NCHUNK, 256, 0, stream>>>(ip, wf, bias, ctx, gpart, ml);
    combine_kernel<<<NBATCH / 4, 256, 0, stream>>>((const float4*)gpart, ml, (float4*)d_out);
}